// Round 11
// baseline (455.196 us; speedup 1.0000x reference)
//
#include <hip/hip_runtime.h>
#include <hip/hip_bf16.h>

#define DIN 768
#define DH  256

typedef unsigned short ushort_t;
typedef __attribute__((ext_vector_type(8))) short short8v;   // 8 bf16 (4 VGPRs)
typedef __attribute__((ext_vector_type(4))) float f32x4;

// stored-col s -> original-col (within each 64-col block):
__host__ __device__ inline int orig_col(int s) {
  return (s & ~63) | (s & 0x20) | ((s & 1) << 4) | ((s >> 1) & 0xF);
}

__device__ inline float wave_sum(float v) {
#pragma unroll
  for (int o = 32; o; o >>= 1) v += __shfl_xor(v, o);
  return v;
}
__device__ inline float leaky(float v) { return v > 0.f ? v : 0.2f * v; }

__device__ inline ushort_t f2bf(float f) {
  union { float f; unsigned u; } v; v.f = f;
  unsigned r = v.u + 0x7FFFu + ((v.u >> 16) & 1u);  // RNE
  return (ushort_t)(r >> 16);
}
__device__ inline float bf2f(ushort_t u) {
  union { unsigned u; float f; } t; t.u = ((unsigned)u) << 16; return t.f;
}

__device__ inline void unpack8(uint4 v, float* f) {
  union { unsigned u; float f; } t;
  t.u = v.x << 16;         f[0] = t.f;
  t.u = v.x & 0xFFFF0000u; f[1] = t.f;
  t.u = v.y << 16;         f[2] = t.f;
  t.u = v.y & 0xFFFF0000u; f[3] = t.f;
  t.u = v.z << 16;         f[4] = t.f;
  t.u = v.z & 0xFFFF0000u; f[5] = t.f;
  t.u = v.w << 16;         f[6] = t.f;
  t.u = v.w & 0xFFFF0000u; f[7] = t.f;
}
__device__ inline uint4 pack8(const float* f) {
  uint4 o;
  o.x = (unsigned)f2bf(f[0]) | ((unsigned)f2bf(f[1]) << 16);
  o.y = (unsigned)f2bf(f[2]) | ((unsigned)f2bf(f[3]) << 16);
  o.z = (unsigned)f2bf(f[4]) | ((unsigned)f2bf(f[5]) << 16);
  o.w = (unsigned)f2bf(f[6]) | ((unsigned)f2bf(f[7]) << 16);
  return o;
}

// ---------------- K1: cosine gate + bf16(x*rel), fused dst-histogram (R9 form) -----
__global__ __launch_bounds__(256) void relxb_hist_kernel(
    const float* __restrict__ ce, const float* __restrict__ x,
    const int* __restrict__ batch, ushort_t* __restrict__ xb, int n,
    const int* __restrict__ edst, int E, int* __restrict__ cnt) {
  int node = blockIdx.x * 4 + (threadIdx.x >> 6);
  int lane = threadIdx.x & 63;
  if (node < n) {
    int g = batch[node];
    const float4* xr = (const float4*)(x + (size_t)node * DIN);
    const float4* cr = (const float4*)(ce + (size_t)g * DIN);
    float4 av[3];
    float dxy = 0.f, dxx = 0.f, dcc = 0.f;
#pragma unroll
    for (int i = 0; i < 3; i++) {
      float4 a = xr[lane + 64 * i];
      float4 b = cr[lane + 64 * i];
      av[i] = a;
      dxy += a.x*b.x + a.y*b.y + a.z*b.z + a.w*b.w;
      dxx += a.x*a.x + a.y*a.y + a.z*a.z + a.w*a.w;
      dcc += b.x*b.x + b.y*b.y + b.z*b.z + b.w*b.w;
    }
    dxy = wave_sum(dxy);
    dxx = wave_sum(dxx);
    dcc = wave_sum(dcc);
    float denom = fmaxf(sqrtf(dxx) * sqrtf(dcc), 1e-8f);
    float rel = dxy / denom;
#pragma unroll
    for (int i = 0; i < 3; i++) {
      float4 a = av[i];
      ushort4 o = make_ushort4(f2bf(a.x * rel), f2bf(a.y * rel),
                               f2bf(a.z * rel), f2bf(a.w * rel));
      *(ushort4*)&xb[(size_t)node * DIN + (lane + 64 * i) * 4] = o;
    }
  }
  // fused histogram (grid-stride over edges)
  for (int e = blockIdx.x * blockDim.x + threadIdx.x; e < E;
       e += gridDim.x * blockDim.x)
    atomicAdd(&cnt[edst[e]], 1);
}

// ---------------- prep: one 64x64 tile per block (48 Wt1 + 16 Wt2 + 1 vectors) -----
__global__ __launch_bounds__(256) void prep_kernel(
    const float* __restrict__ W1, const float* __restrict__ W2,
    const float* __restrict__ b1, const float* __restrict__ b2,
    const float* __restrict__ gamma, const float* __restrict__ beta,
    const float* __restrict__ Wc,
    ushort_t* __restrict__ Wt1, ushort_t* __restrict__ Wt2,
    float* __restrict__ pb1, float* __restrict__ pb2,
    float* __restrict__ pgamma, float* __restrict__ pbeta,
    float* __restrict__ pWc) {
  __shared__ float tile[64][65];
  int b = blockIdx.x;
  int t = threadIdx.x;
  int r4 = t >> 6;      // wave id 0..3
  int c64 = t & 63;
  if (b < 48) {         // Wt1[c][k] = W1[k][c]; k-tile 0..11, c-tile 0..3
    int k0 = (b % 12) * 64, c0 = (b / 12) * 64;
#pragma unroll
    for (int rr = 0; rr < 16; rr++) {
      int r = rr * 4 + r4;
      tile[r][c64] = W1[(size_t)(k0 + r) * 256 + c0 + c64];
    }
    __syncthreads();
#pragma unroll
    for (int rr = 0; rr < 16; rr++) {
      int cc = rr * 4 + r4;
      Wt1[(size_t)(c0 + cc) * DIN + k0 + c64] = f2bf(tile[c64][cc]);
    }
  } else if (b < 64) {  // Wt2[c][k] = W2[orig_col(k)][c]
    int bb = b - 48;
    int k0 = (bb & 3) * 64, c0 = (bb >> 2) * 64;
#pragma unroll
    for (int rr = 0; rr < 16; rr++) {
      int r = rr * 4 + r4;
      tile[r][c64] = W2[(size_t)orig_col(k0 + r) * 256 + c0 + c64];
    }
    __syncthreads();
#pragma unroll
    for (int rr = 0; rr < 16; rr++) {
      int cc = rr * 4 + r4;
      Wt2[(size_t)(c0 + cc) * DH + k0 + c64] = f2bf(tile[c64][cc]);
    }
  } else {              // permuted per-column vectors
    int o = orig_col(t);
    pb1[t] = b1[o];
    pb2[t] = b2[o];
    pgamma[t] = gamma[o];
    pbeta[t] = beta[o];
    pWc[t] = Wc[o];
  }
}

// ---------------- CSR scan + fill ----------------
__global__ __launch_bounds__(1024) void scan_kernel(const int* __restrict__ cnt,
                                                    int* __restrict__ row_off, int n) {
  __shared__ int s[1024];
  int t = threadIdx.x;
  int chunk = (n + 1023) / 1024;
  int lo = t * chunk, hi = min(lo + chunk, n);
  int sum = 0;
  for (int i = lo; i < hi; i++) sum += cnt[i];
  int mysum = sum;
  s[t] = sum;
  __syncthreads();
  for (int off = 1; off < 1024; off <<= 1) {
    int v = (t >= off) ? s[t - off] : 0;
    __syncthreads();
    s[t] += v;
    __syncthreads();
  }
  int run = s[t] - mysum;
  for (int i = lo; i < hi; i++) { row_off[i] = run; run += cnt[i]; }
  if (t == 1023) row_off[n] = s[1023];
}

__global__ void fill_kernel(const int* __restrict__ src, const int* __restrict__ dst, int E,
                            const int* __restrict__ row_off, int* __restrict__ fill,
                            int* __restrict__ col_src) {
  for (int e = blockIdx.x * blockDim.x + threadIdx.x; e < E; e += gridDim.x * blockDim.x) {
    int d = dst[e];
    int slot = row_off[d] + atomicAdd(&fill[d], 1);
    col_src[slot] = src[e];
  }
}

// ---------------- bf16 MFMA GEMM + fused alpha dots ----------------
template <int K>
__global__ __launch_bounds__(256) void gemm_mfma(
    const ushort_t* __restrict__ A, const ushort_t* __restrict__ Bt,
    ushort_t* __restrict__ C, const float* __restrict__ a_s,
    const float* __restrict__ a_d, float* __restrict__ alpha_s,
    float* __restrict__ alpha_d, int Mreal) {
  __shared__ ushort_t lds[16384];
  const int tid = threadIdx.x;
  const int lane = tid & 63;
  const int wave = tid >> 6;

  int p = blockIdx.y * 2 + blockIdx.x;
  int total = 2 * gridDim.y;
  int cch = p >> 4;
  int v;
  if ((cch << 4) + 16 <= total) {
    int r = p & 15;
    v = (cch << 4) | ((r & 7) << 1) | (r >> 3);
  } else {
    v = p;
  }
  const int col0 = (v & 1) * 128;
  const int row0 = (v >> 1) * 128;

  const int wr = wave >> 1, wc = wave & 1;
  const int c16 = lane & 15, g4 = lane >> 4;
  const int st_roff = lane >> 3;
  const int st_gsrc = (lane & 7) ^ st_roff;

  f32x4 acc[4][4];
#pragma unroll
  for (int m = 0; m < 4; m++)
#pragma unroll
    for (int nn = 0; nn < 4; nn++)
#pragma unroll
      for (int j = 0; j < 4; j++) acc[m][nn][j] = 0.f;

  for (int k0 = 0; k0 < K; k0 += 64) {
#pragma unroll
    for (int ci = 0; ci < 8; ci++) {
      int inst = wave * 8 + ci;
      int isB = inst >> 4;
      int idx = inst & 15;
      int lrow = idx * 8 + st_roff;
      const ushort_t* gsrc;
      if (isB == 0) {
        int rg = row0 + lrow;
        rg = rg < Mreal ? rg : Mreal - 1;
        gsrc = A + (size_t)rg * K + k0 + st_gsrc * 8;
      } else {
        gsrc = Bt + (size_t)(col0 + lrow) * K + k0 + st_gsrc * 8;
      }
      __builtin_amdgcn_global_load_lds(
          (const __attribute__((address_space(1))) void*)gsrc,
          (__attribute__((address_space(3))) void*)&lds[isB * 8192 + idx * 512],
          16, 0, 0);
    }
    __syncthreads();
#pragma unroll
    for (int ks = 0; ks < 2; ks++) {
      int g = ks * 4 + g4;
      short8v a[4], b[4];
#pragma unroll
      for (int m = 0; m < 4; m++) {
        int ra = wr * 64 + m * 16 + c16;
        a[m] = *(const short8v*)&lds[ra * 64 + (g ^ (ra & 7)) * 8];
      }
#pragma unroll
      for (int nn = 0; nn < 4; nn++) {
        int rb = wc * 64 + nn * 16 + c16;
        b[nn] = *(const short8v*)&lds[8192 + rb * 64 + (g ^ (rb & 7)) * 8];
      }
#pragma unroll
      for (int m = 0; m < 4; m++)
#pragma unroll
        for (int nn = 0; nn < 4; nn++)
          acc[m][nn] = __builtin_amdgcn_mfma_f32_16x16x32_bf16(a[m], b[nn],
                                                               acc[m][nn], 0, 0, 0);
    }
    __syncthreads();
  }

  float asv[4], adv[4];
#pragma unroll
  for (int nn = 0; nn < 4; nn++) {
    int col = col0 + wc * 64 + nn * 16 + c16;
    asv[nn] = a_s[col];
    adv[nn] = a_d[col];
  }

  uint* Cw = (uint*)C;
#pragma unroll
  for (int m = 0; m < 4; m++) {
    int row_base = row0 + wr * 64 + m * 16 + g4 * 4;
#pragma unroll
    for (int j = 0; j < 4; j++) {
      int row = row_base + j;
      float ps = 0.f, pd = 0.f;
#pragma unroll
      for (int nn = 0; nn < 4; nn++) {
        float v2 = acc[m][nn][j];
        ps = fmaf(v2, asv[nn], ps);
        pd = fmaf(v2, adv[nn], pd);
      }
#pragma unroll
      for (int o = 1; o < 16; o <<= 1) {
        ps += __shfl_xor(ps, o);
        pd += __shfl_xor(pd, o);
      }
      if (c16 == 0 && row < Mreal) {
        atomicAdd(&alpha_s[row], ps);
        atomicAdd(&alpha_d[row], pd);
      }
      if (row < Mreal) {
#pragma unroll
        for (int q = 0; q < 2; q++) {
          unsigned wv = (unsigned)f2bf(acc[m][2 * q][j]) |
                        ((unsigned)f2bf(acc[m][2 * q + 1][j]) << 16);
          Cw[(size_t)row * 128 + (col0 >> 1) + wc * 32 + q * 16 + c16] = wv;
        }
      }
    }
  }
}

// ---------------- GAT aggregation: single pass, 4-deep gather ----------------
__global__ __launch_bounds__(256) void gat_agg(
    const ushort_t* __restrict__ hb, const float* __restrict__ as_,
    const float* __restrict__ ad_, const int* __restrict__ row_off,
    const int* __restrict__ col_src, const float* __restrict__ bias,
    ushort_t* __restrict__ outb, int n, int relu_out) {
  int node = blockIdx.x * 4 + (threadIdx.x >> 6);
  int lane = threadIdx.x & 63;
  if (node >= n) return;
  int lo = row_off[node], hi = row_off[node + 1];
  int deg = hi - lo;
  float adn = ad_[node];
  float w_self = __expf(leaky(as_[node] + adn));

  const int q = lane >> 4;
  const int l16 = lane & 15;
  const ushort_t* rowbase = hb + (size_t)l16 * 16;

  float acc[16];
  float zacc = (lane == 0) ? w_self : 0.f;
  {
    const uint4* ps = (const uint4*)(rowbase + (size_t)node * 256);
    uint4 v0 = ps[0], v1 = ps[1];
    float ws = (q == 0) ? w_self : 0.f;
    float f[16];
    unpack8(v0, f);
    unpack8(v1, f + 8);
#pragma unroll
    for (int i = 0; i < 16; i++) acc[i] = ws * f[i];
  }

  for (int base = 0; base < deg; base += 64) {
    int cnt = min(64, deg - base);
    int s = 0; float w = 0.f;
    if (lane < cnt) {
      s = col_src[lo + base + lane];
      w = __expf(leaky(as_[s] + adn));
    }
    zacc += w;
    int e = 0;
    // 4 rows in flight per quarter-lane (covers deg<=16 in ONE latency round)
    for (; e + 16 <= cnt; e += 16) {
      int i0 = e + q, i1 = e + 4 + q, i2 = e + 8 + q, i3 = e + 12 + q;
      int s0 = __shfl(s, i0), s1 = __shfl(s, i1);
      int s2 = __shfl(s, i2), s3 = __shfl(s, i3);
      float w0 = __shfl(w, i0), w1 = __shfl(w, i1);
      float w2 = __shfl(w, i2), w3 = __shfl(w, i3);
      const uint4* p0 = (const uint4*)(rowbase + (size_t)s0 * 256);
      const uint4* p1 = (const uint4*)(rowbase + (size_t)s1 * 256);
      const uint4* p2 = (const uint4*)(rowbase + (size_t)s2 * 256);
      const uint4* p3 = (const uint4*)(rowbase + (size_t)s3 * 256);
      uint4 A0 = p0[0], A1 = p0[1];
      uint4 B0 = p1[0], B1 = p1[1];
      uint4 C0 = p2[0], C1 = p2[1];
      uint4 D0 = p3[0], D1 = p3[1];
      float f[16];
      unpack8(A0, f); unpack8(A1, f + 8);
#pragma unroll
      for (int i = 0; i < 16; i++) acc[i] = fmaf(w0, f[i], acc[i]);
      unpack8(B0, f); unpack8(B1, f + 8);
#pragma unroll
      for (int i = 0; i < 16; i++) acc[i] = fmaf(w1, f[i], acc[i]);
      unpack8(C0, f); unpack8(C1, f + 8);
#pragma unroll
      for (int i = 0; i < 16; i++) acc[i] = fmaf(w2, f[i], acc[i]);
      unpack8(D0, f); unpack8(D1, f + 8);
#pragma unroll
      for (int i = 0; i < 16; i++) acc[i] = fmaf(w3, f[i], acc[i]);
    }
    for (; e + 8 <= cnt; e += 8) {
      int iA = e + q, iB = e + 4 + q;
      int sA = __shfl(s, iA);
      float wA = __shfl(w, iA);
      int sB = __shfl(s, iB);
      float wB = __shfl(w, iB);
      const uint4* pA = (const uint4*)(rowbase + (size_t)sA * 256);
      const uint4* pB = (const uint4*)(rowbase + (size_t)sB * 256);
      uint4 a0 = pA[0], a1 = pA[1];
      uint4 b0 = pB[0], b1 = pB[1];
      float f[16];
      unpack8(a0, f); unpack8(a1, f + 8);
#pragma unroll
      for (int i = 0; i < 16; i++) acc[i] = fmaf(wA, f[i], acc[i]);
      unpack8(b0, f); unpack8(b1, f + 8);
#pragma unroll
      for (int i = 0; i < 16; i++) acc[i] = fmaf(wB, f[i], acc[i]);
    }
    for (; e < cnt; e += 4) {
      int myE = e + q;
      int idx = myE < cnt ? myE : cnt - 1;
      int ss = __shfl(s, idx);
      float wv = __shfl(w, idx);
      float wgt = (myE < cnt) ? wv : 0.f;
      const uint4* pp = (const uint4*)(rowbase + (size_t)ss * 256);
      uint4 v0 = pp[0], v1 = pp[1];
      float f[16];
      unpack8(v0, f); unpack8(v1, f + 8);
#pragma unroll
      for (int i = 0; i < 16; i++) acc[i] = fmaf(wgt, f[i], acc[i]);
    }
  }

  float z = wave_sum(zacc);
  float inv_z = 1.0f / z;

#pragma unroll
  for (int i = 0; i < 16; i++) {
    acc[i] += __shfl_xor(acc[i], 16);
    acc[i] += __shfl_xor(acc[i], 32);
  }

  if (q == 0) {
    float o[16];
#pragma unroll
    for (int i = 0; i < 16; i += 4) {
      float4 bb = *(const float4*)&bias[l16 * 16 + i];
      o[i]     = fmaf(acc[i],     inv_z, bb.x);
      o[i + 1] = fmaf(acc[i + 1], inv_z, bb.y);
      o[i + 2] = fmaf(acc[i + 2], inv_z, bb.z);
      o[i + 3] = fmaf(acc[i + 3], inv_z, bb.w);
    }
    if (relu_out) {
#pragma unroll
      for (int i = 0; i < 16; i++) o[i] = fmaxf(o[i], 0.f);
    }
    uint4* op = (uint4*)(outb + (size_t)node * 256 + l16 * 16);
    op[0] = pack8(o);
    op[1] = pack8(o + 8);
  }
}

// ---------------- BN stats (bf16 input, stored space) ----------------
__global__ __launch_bounds__(256) void bn_stats(const ushort_t* __restrict__ h, int n,
                                                float* __restrict__ bsum,
                                                float* __restrict__ bsq) {
  int c = threadIdx.x;
  int rows_per_block = (n + gridDim.x - 1) / gridDim.x;
  int r0 = blockIdx.x * rows_per_block;
  int r1 = min(r0 + rows_per_block, n);
  float sum = 0.f, sq = 0.f;
  for (int r = r0; r < r1; r++) {
    float v = bf2f(h[(size_t)r * 256 + c]);
    sum += v;
    sq = fmaf(v, v, sq);
  }
  atomicAdd(&bsum[c], sum);
  atomicAdd(&bsq[c], sq);
}

// ---------------- BN apply + ReLU (bf16 -> bf16, stored space) ----------------
__global__ __launch_bounds__(256) void bn_apply(const ushort_t* __restrict__ h,
                                                const float* __restrict__ bsum,
                                                const float* __restrict__ bsq,
                                                const float* __restrict__ gamma,
                                                const float* __restrict__ beta,
                                                ushort_t* __restrict__ h2b, int n) {
  int total4 = n * 64;
  float inv_n = 1.0f / (float)n;
  for (int f = blockIdx.x * blockDim.x + threadIdx.x; f < total4;
       f += gridDim.x * blockDim.x) {
    int c4 = f & 63;
    uint2 hv = ((const uint2*)h)[f];
    float v0, v1, v2, v3;
    {
      union { unsigned u; float fl; } t;
      t.u = hv.x << 16;         v0 = t.fl;
      t.u = hv.x & 0xFFFF0000u; v1 = t.fl;
      t.u = hv.y << 16;         v2 = t.fl;
      t.u = hv.y & 0xFFFF0000u; v3 = t.fl;
    }
    float4 sm = ((const float4*)bsum)[c4];
    float4 sl = ((const float4*)bsq)[c4];
    float4 g = ((const float4*)gamma)[c4];
    float4 bb = ((const float4*)beta)[c4];
    float m, var;
    m = sm.x * inv_n; var = sl.x * inv_n - m * m;
    v0 = fmaxf(g.x * (v0 - m) * rsqrtf(var + 1e-5f) + bb.x, 0.f);
    m = sm.y * inv_n; var = sl.y * inv_n - m * m;
    v1 = fmaxf(g.y * (v1 - m) * rsqrtf(var + 1e-5f) + bb.y, 0.f);
    m = sm.z * inv_n; var = sl.z * inv_n - m * m;
    v2 = fmaxf(g.z * (v2 - m) * rsqrtf(var + 1e-5f) + bb.z, 0.f);
    m = sm.w * inv_n; var = sl.w * inv_n - m * m;
    v3 = fmaxf(g.w * (v3 - m) * rsqrtf(var + 1e-5f) + bb.w, 0.f);
    uint2 o;
    o.x = (unsigned)f2bf(v0) | ((unsigned)f2bf(v1) << 16);
    o.y = (unsigned)f2bf(v2) | ((unsigned)f2bf(v3) << 16);
    ((uint2*)h2b)[f] = o;
  }
}

// ---------------- mean pool: partial sums ----------------
__device__ inline int lower_bound_dev(const int* a, int n, int v) {
  int lo = 0, hi = n;
  while (lo < hi) {
    int mid = (lo + hi) >> 1;
    if (a[mid] < v) lo = mid + 1; else hi = mid;
  }
  return lo;
}

#define POOL_CHUNKS 16
__global__ __launch_bounds__(256) void pool_partial(const ushort_t* __restrict__ h,
                                                    const int* __restrict__ batch, int n,
                                                    float* __restrict__ psum) {
  int g = blockIdx.x / POOL_CHUNKS;
  int c = blockIdx.x % POOL_CHUNKS;
  int lo = lower_bound_dev(batch, n, g);
  int hi = lower_bound_dev(batch, n, g + 1);
  int len = hi - lo;
  int r0 = lo + (int)(((long long)len * c) / POOL_CHUNKS);
  int r1 = lo + (int)(((long long)len * (c + 1)) / POOL_CHUNKS);
  if (r1 <= r0) return;
  float sum = 0.f;
  for (int r = r0; r < r1; r++) sum += bf2f(h[(size_t)r * 256 + threadIdx.x]);
  atomicAdd(&psum[(size_t)g * 256 + threadIdx.x], sum);
}

// ---------------- final head ----------------
__global__ __launch_bounds__(256) void final_kernel(const float* __restrict__ psum,
                                                    const int* __restrict__ batch, int n,
                                                    const float* __restrict__ ce,
                                                    const float* __restrict__ pWc,
                                                    const float* __restrict__ Wc,
                                                    const float* __restrict__ bc,
                                                    float* __restrict__ out, int B) {
  int g = blockIdx.x;
  int t = threadIdx.x;
  int lo = lower_bound_dev(batch, n, g);
  int hi = lower_bound_dev(batch, n, g + 1);
  float inv_cnt = 1.0f / fmaxf((float)(hi - lo), 1.0f);
  float p = 0.f;
  p = fmaf(psum[(size_t)g * 256 + t] * inv_cnt, pWc[t], p);
  p = fmaf(ce[(size_t)g * 768 + t],        Wc[256 + t], p);
  p = fmaf(ce[(size_t)g * 768 + 256 + t],  Wc[512 + t], p);
  p = fmaf(ce[(size_t)g * 768 + 512 + t],  Wc[768 + t], p);
  __shared__ float red[256];
  red[t] = p;
  __syncthreads();
  for (int s = 128; s; s >>= 1) {
    if (t < s) red[t] += red[t + s];
    __syncthreads();
  }
  if (t == 0) out[g] = red[0] + bc[0];
}

// ---------------- launch ----------------
extern "C" void kernel_launch(void* const* d_in, const int* in_sizes, int n_in,
                              void* d_out, int out_size, void* d_ws, size_t ws_size,
                              hipStream_t stream) {
  const float* ce    = (const float*)d_in[0];
  const float* x     = (const float*)d_in[1];
  const int*   edge  = (const int*)d_in[2];
  const int*   batch = (const int*)d_in[3];
  const float* W1    = (const float*)d_in[4];
  const float* a_s1  = (const float*)d_in[5];
  const float* a_d1  = (const float*)d_in[6];
  const float* b1    = (const float*)d_in[7];
  const float* W2    = (const float*)d_in[8];
  const float* a_s2  = (const float*)d_in[9];
  const float* a_d2  = (const float*)d_in[10];
  const float* b2    = (const float*)d_in[11];
  const float* gamma = (const float*)d_in[12];
  const float* beta  = (const float*)d_in[13];
  const float* Wc    = (const float*)d_in[14];
  const float* bc    = (const float*)d_in[15];

  const int B = in_sizes[0] / DIN;
  const int n = in_sizes[1] / DIN;
  const int E = in_sizes[2] / 2;
  const int* esrc = edge;
  const int* edst = edge + E;

  char* w = (char*)d_ws;
  size_t off = 0;
  auto carve = [&](size_t bytes) -> void* {
    void* p = w + off;
    off = (off + bytes + 255) & ~(size_t)255;
    return p;
  };
  size_t hbytes = (size_t)n * DH * 2;            // 25.6 MB
  char*  R1      = (char*)carve((size_t)n * DIN * 2);
  ushort_t* xb    = (ushort_t*)R1;
  ushort_t* h1b   = (ushort_t*)R1;
  ushort_t* h2b   = (ushort_t*)(R1 + hbytes);
  ushort_t* buf_ob = (ushort_t*)(R1 + 2 * hbytes);
  ushort_t* buf_hb = (ushort_t*)carve(hbytes);   // GEMM output (both layers)
  int*   row_off = (int*)carve((size_t)(n + 1) * 4);
  int*   col_src = (int*)carve((size_t)E * 4);
  ushort_t* Wt1  = (ushort_t*)carve((size_t)DIN * DH * 2);
  ushort_t* Wt2  = (ushort_t*)carve((size_t)DH * DH * 2);
  float* pb1     = (float*)carve(DH * 4);
  float* pb2     = (float*)carve(DH * 4);
  float* pgamma  = (float*)carve(DH * 4);
  float* pbeta   = (float*)carve(DH * 4);
  float* pWc     = (float*)carve(DH * 4);
  char* zero0 = (char*)carve((size_t)n * 4);     // cnt
  int*   cnt     = (int*)zero0;
  int*   fill    = (int*)carve((size_t)n * 4);
  float* as1buf  = (float*)carve((size_t)n * 4);
  float* ad1buf  = (float*)carve((size_t)n * 4);
  float* as2buf  = (float*)carve((size_t)n * 4);
  float* ad2buf  = (float*)carve((size_t)n * 4);
  float* bn_sum  = (float*)carve(DH * 4);
  float* bn_sq   = (float*)carve(DH * 4);
  float* psum    = (float*)carve((size_t)B * DH * 4);
  size_t zero_bytes = (size_t)((char*)(psum + (size_t)B * DH) - zero0);

  hipMemsetAsync(zero0, 0, zero_bytes, stream);

  const int gN4 = (n + 3) / 4;
  const int Mb = (n + 127) / 128;

  prep_kernel<<<65, 256, 0, stream>>>(W1, W2, b1, b2, gamma, beta, Wc,
                                      Wt1, Wt2, pb1, pb2, pgamma, pbeta, pWc);
  relxb_hist_kernel<<<gN4, 256, 0, stream>>>(ce, x, batch, xb, n, edst, E, cnt);
  scan_kernel<<<1, 1024, 0, stream>>>(cnt, row_off, n);
  fill_kernel<<<1024, 256, 0, stream>>>(esrc, edst, E, row_off, fill, col_src);

  // ---- layer 1 ----
  gemm_mfma<DIN><<<dim3(2, Mb), 256, 0, stream>>>(xb, Wt1, buf_hb, a_s1, a_d1,
                                                  as1buf, ad1buf, n);
  gat_agg<<<gN4, 256, 0, stream>>>(buf_hb, as1buf, ad1buf, row_off, col_src, pb1,
                                   h1b, n, 0);
  bn_stats<<<512, 256, 0, stream>>>(h1b, n, bn_sum, bn_sq);
  bn_apply<<<2048, 256, 0, stream>>>(h1b, bn_sum, bn_sq, pgamma, pbeta, h2b, n);

  // ---- layer 2 ----
  gemm_mfma<DH><<<dim3(2, Mb), 256, 0, stream>>>(h2b, Wt2, buf_hb, a_s2, a_d2,
                                                 as2buf, ad2buf, n);
  gat_agg<<<gN4, 256, 0, stream>>>(buf_hb, as2buf, ad2buf, row_off, col_src, pb2,
                                   buf_ob, n, 1);

  // ---- head ----
  pool_partial<<<B * POOL_CHUNKS, 256, 0, stream>>>(buf_ob, batch, n, psum);
  final_kernel<<<B, 256, 0, stream>>>(psum, batch, n, ce, pWc, Wc, bc,
                                      (float*)d_out, B);
}

// Round 12
// 417.779 us; speedup vs baseline: 1.0896x; 1.0896x over previous
//
#include <hip/hip_runtime.h>
#include <hip/hip_bf16.h>

#define DIN 768
#define DH  256

typedef unsigned short ushort_t;
typedef __attribute__((ext_vector_type(8))) short short8v;   // 8 bf16 (4 VGPRs)
typedef __attribute__((ext_vector_type(4))) float f32x4;

// stored-col s -> original-col (within each 64-col block):
__host__ __device__ inline int orig_col(int s) {
  return (s & ~63) | (s & 0x20) | ((s & 1) << 4) | ((s >> 1) & 0xF);
}

__device__ inline float wave_sum(float v) {
#pragma unroll
  for (int o = 32; o; o >>= 1) v += __shfl_xor(v, o);
  return v;
}
// two interleaved butterfly reductions (independent chains -> ILP)
__device__ inline void wave_sum2(float& a, float& b) {
#pragma unroll
  for (int o = 32; o; o >>= 1) {
    a += __shfl_xor(a, o);
    b += __shfl_xor(b, o);
  }
}
__device__ inline float leaky(float v) { return v > 0.f ? v : 0.2f * v; }

__device__ inline ushort_t f2bf(float f) {
  union { float f; unsigned u; } v; v.f = f;
  unsigned r = v.u + 0x7FFFu + ((v.u >> 16) & 1u);  // RNE
  return (ushort_t)(r >> 16);
}
__device__ inline float bf2f(ushort_t u) {
  union { unsigned u; float f; } t; t.u = ((unsigned)u) << 16; return t.f;
}

__device__ inline void unpack8(uint4 v, float* f) {
  union { unsigned u; float f; } t;
  t.u = v.x << 16;         f[0] = t.f;
  t.u = v.x & 0xFFFF0000u; f[1] = t.f;
  t.u = v.y << 16;         f[2] = t.f;
  t.u = v.y & 0xFFFF0000u; f[3] = t.f;
  t.u = v.z << 16;         f[4] = t.f;
  t.u = v.z & 0xFFFF0000u; f[5] = t.f;
  t.u = v.w << 16;         f[6] = t.f;
  t.u = v.w & 0xFFFF0000u; f[7] = t.f;
}
__device__ inline uint4 pack8(const float* f) {
  uint4 o;
  o.x = (unsigned)f2bf(f[0]) | ((unsigned)f2bf(f[1]) << 16);
  o.y = (unsigned)f2bf(f[2]) | ((unsigned)f2bf(f[3]) << 16);
  o.z = (unsigned)f2bf(f[4]) | ((unsigned)f2bf(f[5]) << 16);
  o.w = (unsigned)f2bf(f[6]) | ((unsigned)f2bf(f[7]) << 16);
  return o;
}

// ---------------- K1: cosine gate (rel only) + bf16(x) cast + fused histogram ------
// Stores unscaled bf16(x) immediately (independent of the reduction); rel applied
// later in GEMM1's epilogue. ||ce_g|| precomputed per graph (cenorm).
__global__ __launch_bounds__(256) void relxb_hist_kernel(
    const float* __restrict__ ce, const float* __restrict__ x,
    const int* __restrict__ batch, const float* __restrict__ cenorm,
    ushort_t* __restrict__ xb, float* __restrict__ rel, int n,
    const int* __restrict__ edst, int E, int* __restrict__ cnt) {
  int node = blockIdx.x * 4 + (threadIdx.x >> 6);
  int lane = threadIdx.x & 63;
  if (node < n) {
    int g = batch[node];
    const float4* xr = (const float4*)(x + (size_t)node * DIN);
    const float4* cr = (const float4*)(ce + (size_t)g * DIN);
    float dxy = 0.f, dxx = 0.f;
#pragma unroll
    for (int i = 0; i < 3; i++) {
      float4 a = xr[lane + 64 * i];
      float4 b = cr[lane + 64 * i];
      // store cast(x) right away — no dependence on the reduction
      ushort4 o = make_ushort4(f2bf(a.x), f2bf(a.y), f2bf(a.z), f2bf(a.w));
      *(ushort4*)&xb[(size_t)node * DIN + (lane + 64 * i) * 4] = o;
      dxy += a.x*b.x + a.y*b.y + a.z*b.z + a.w*b.w;
      dxx += a.x*a.x + a.y*a.y + a.z*a.z + a.w*a.w;
    }
    wave_sum2(dxy, dxx);
    if (lane == 0) {
      float denom = fmaxf(sqrtf(dxx) * cenorm[g], 1e-8f);
      rel[node] = dxy / denom;
    }
  }
  // fused histogram (grid-stride over edges)
  for (int e = blockIdx.x * blockDim.x + threadIdx.x; e < E;
       e += gridDim.x * blockDim.x)
    atomicAdd(&cnt[edst[e]], 1);
}

// ---------------- prep: Wt tiles + permuted vectors + per-graph ce norms ----------
__global__ __launch_bounds__(256) void prep_kernel(
    const float* __restrict__ W1, const float* __restrict__ W2,
    const float* __restrict__ b1, const float* __restrict__ b2,
    const float* __restrict__ gamma, const float* __restrict__ beta,
    const float* __restrict__ Wc, const float* __restrict__ ce,
    ushort_t* __restrict__ Wt1, ushort_t* __restrict__ Wt2,
    float* __restrict__ pb1, float* __restrict__ pb2,
    float* __restrict__ pgamma, float* __restrict__ pbeta,
    float* __restrict__ pWc, float* __restrict__ cenorm, int B) {
  __shared__ float tile[64][65];
  int b = blockIdx.x;
  int t = threadIdx.x;
  int r4 = t >> 6;      // wave id 0..3
  int c64 = t & 63;
  if (b < 48) {         // Wt1[c][k] = W1[k][c]; k-tile 0..11, c-tile 0..3
    int k0 = (b % 12) * 64, c0 = (b / 12) * 64;
#pragma unroll
    for (int rr = 0; rr < 16; rr++) {
      int r = rr * 4 + r4;
      tile[r][c64] = W1[(size_t)(k0 + r) * 256 + c0 + c64];
    }
    __syncthreads();
#pragma unroll
    for (int rr = 0; rr < 16; rr++) {
      int cc = rr * 4 + r4;
      Wt1[(size_t)(c0 + cc) * DIN + k0 + c64] = f2bf(tile[c64][cc]);
    }
  } else if (b < 64) {  // Wt2[c][k] = W2[orig_col(k)][c]
    int bb = b - 48;
    int k0 = (bb & 3) * 64, c0 = (bb >> 2) * 64;
#pragma unroll
    for (int rr = 0; rr < 16; rr++) {
      int r = rr * 4 + r4;
      tile[r][c64] = W2[(size_t)orig_col(k0 + r) * 256 + c0 + c64];
    }
    __syncthreads();
#pragma unroll
    for (int rr = 0; rr < 16; rr++) {
      int cc = rr * 4 + r4;
      Wt2[(size_t)(c0 + cc) * DH + k0 + c64] = f2bf(tile[c64][cc]);
    }
  } else if (b == 64) { // permuted per-column vectors
    int o = orig_col(t);
    pb1[t] = b1[o];
    pb2[t] = b2[o];
    pgamma[t] = gamma[o];
    pbeta[t] = beta[o];
    pWc[t] = Wc[o];
  } else {              // per-graph ||ce|| (wave per graph, strided)
    int lane = t & 63;
    for (int g = r4; g < B; g += 4) {
      const float4* cr = (const float4*)(ce + (size_t)g * DIN);
      float s = 0.f;
#pragma unroll
      for (int i = 0; i < 3; i++) {
        float4 v = cr[lane + 64 * i];
        s += v.x*v.x + v.y*v.y + v.z*v.z + v.w*v.w;
      }
      s = wave_sum(s);
      if (lane == 0) cenorm[g] = sqrtf(s);
    }
  }
}

// ---------------- CSR: parallel 3-phase scan + fill ----------------
__global__ __launch_bounds__(256) void scan1_kernel(const int* __restrict__ cnt,
                                                    int* __restrict__ row_off,
                                                    int* __restrict__ bsum, int n) {
  __shared__ int s[256];
  int t = threadIdx.x;
  int i = blockIdx.x * 256 + t;
  int v = (i < n) ? cnt[i] : 0;
  s[t] = v;
  __syncthreads();
  for (int off = 1; off < 256; off <<= 1) {
    int tmp = (t >= off) ? s[t - off] : 0;
    __syncthreads();
    s[t] += tmp;
    __syncthreads();
  }
  if (i < n) row_off[i] = s[t] - v;  // local exclusive prefix
  if (t == 255) bsum[blockIdx.x] = s[255];
}

__global__ __launch_bounds__(256) void scan2_kernel(const int* __restrict__ bsum,
                                                    int* __restrict__ boff, int nb,
                                                    int* __restrict__ row_off, int n) {
  __shared__ int s[256];
  int t = threadIdx.x;
  int v = (t < nb) ? bsum[t] : 0;
  s[t] = v;
  __syncthreads();
  for (int off = 1; off < 256; off <<= 1) {
    int tmp = (t >= off) ? s[t - off] : 0;
    __syncthreads();
    s[t] += tmp;
    __syncthreads();
  }
  if (t < nb) boff[t] = s[t] - v;
  if (t == nb - 1) row_off[n] = s[t];  // grand total
}

__global__ __launch_bounds__(256) void scan3_kernel(int* __restrict__ row_off,
                                                    const int* __restrict__ boff, int n) {
  int i = blockIdx.x * 256 + threadIdx.x;
  if (i < n) row_off[i] += boff[blockIdx.x];
}

__global__ void fill_kernel(const int* __restrict__ src, const int* __restrict__ dst, int E,
                            const int* __restrict__ row_off, int* __restrict__ fill,
                            int* __restrict__ col_src) {
  for (int e = blockIdx.x * blockDim.x + threadIdx.x; e < E; e += gridDim.x * blockDim.x) {
    int d = dst[e];
    int slot = row_off[d] + atomicAdd(&fill[d], 1);
    col_src[slot] = src[e];
  }
}

// ---------------- bf16 MFMA GEMM + row-scale + fused alpha dots ----------------
template <int K>
__global__ __launch_bounds__(256) void gemm_mfma(
    const ushort_t* __restrict__ A, const ushort_t* __restrict__ Bt,
    ushort_t* __restrict__ C, const float* __restrict__ scale,
    const float* __restrict__ a_s, const float* __restrict__ a_d,
    float* __restrict__ alpha_s, float* __restrict__ alpha_d, int Mreal) {
  __shared__ ushort_t lds[16384];
  const int tid = threadIdx.x;
  const int lane = tid & 63;
  const int wave = tid >> 6;

  int p = blockIdx.y * 2 + blockIdx.x;
  int total = 2 * gridDim.y;
  int cch = p >> 4;
  int v;
  if ((cch << 4) + 16 <= total) {
    int r = p & 15;
    v = (cch << 4) | ((r & 7) << 1) | (r >> 3);
  } else {
    v = p;
  }
  const int col0 = (v & 1) * 128;
  const int row0 = (v >> 1) * 128;

  const int wr = wave >> 1, wc = wave & 1;
  const int c16 = lane & 15, g4 = lane >> 4;
  const int st_roff = lane >> 3;
  const int st_gsrc = (lane & 7) ^ st_roff;

  f32x4 acc[4][4];
#pragma unroll
  for (int m = 0; m < 4; m++)
#pragma unroll
    for (int nn = 0; nn < 4; nn++)
#pragma unroll
      for (int j = 0; j < 4; j++) acc[m][nn][j] = 0.f;

  for (int k0 = 0; k0 < K; k0 += 64) {
#pragma unroll
    for (int ci = 0; ci < 8; ci++) {
      int inst = wave * 8 + ci;
      int isB = inst >> 4;
      int idx = inst & 15;
      int lrow = idx * 8 + st_roff;
      const ushort_t* gsrc;
      if (isB == 0) {
        int rg = row0 + lrow;
        rg = rg < Mreal ? rg : Mreal - 1;
        gsrc = A + (size_t)rg * K + k0 + st_gsrc * 8;
      } else {
        gsrc = Bt + (size_t)(col0 + lrow) * K + k0 + st_gsrc * 8;
      }
      __builtin_amdgcn_global_load_lds(
          (const __attribute__((address_space(1))) void*)gsrc,
          (__attribute__((address_space(3))) void*)&lds[isB * 8192 + idx * 512],
          16, 0, 0);
    }
    __syncthreads();
#pragma unroll
    for (int ks = 0; ks < 2; ks++) {
      int g = ks * 4 + g4;
      short8v a[4], b[4];
#pragma unroll
      for (int m = 0; m < 4; m++) {
        int ra = wr * 64 + m * 16 + c16;
        a[m] = *(const short8v*)&lds[ra * 64 + (g ^ (ra & 7)) * 8];
      }
#pragma unroll
      for (int nn = 0; nn < 4; nn++) {
        int rb = wc * 64 + nn * 16 + c16;
        b[nn] = *(const short8v*)&lds[8192 + rb * 64 + (g ^ (rb & 7)) * 8];
      }
#pragma unroll
      for (int m = 0; m < 4; m++)
#pragma unroll
        for (int nn = 0; nn < 4; nn++)
          acc[m][nn] = __builtin_amdgcn_mfma_f32_16x16x32_bf16(a[m], b[nn],
                                                               acc[m][nn], 0, 0, 0);
    }
    __syncthreads();
  }

  float asv[4], adv[4];
#pragma unroll
  for (int nn = 0; nn < 4; nn++) {
    int col = col0 + wc * 64 + nn * 16 + c16;
    asv[nn] = a_s[col];
    adv[nn] = a_d[col];
  }

  uint* Cw = (uint*)C;
#pragma unroll
  for (int m = 0; m < 4; m++) {
    int row_base = row0 + wr * 64 + m * 16 + g4 * 4;
#pragma unroll
    for (int j = 0; j < 4; j++) {
      int row = row_base + j;
      int rc = row < Mreal ? row : Mreal - 1;
      float s = scale ? scale[rc] : 1.0f;
      float vs[4];
      float ps = 0.f, pd = 0.f;
#pragma unroll
      for (int nn = 0; nn < 4; nn++) {
        float v2 = acc[m][nn][j] * s;
        vs[nn] = v2;
        ps = fmaf(v2, asv[nn], ps);
        pd = fmaf(v2, adv[nn], pd);
      }
#pragma unroll
      for (int o = 1; o < 16; o <<= 1) {
        ps += __shfl_xor(ps, o);
        pd += __shfl_xor(pd, o);
      }
      if (c16 == 0 && row < Mreal) {
        atomicAdd(&alpha_s[row], ps);
        atomicAdd(&alpha_d[row], pd);
      }
      if (row < Mreal) {
#pragma unroll
        for (int q = 0; q < 2; q++) {
          unsigned wv = (unsigned)f2bf(vs[2 * q]) |
                        ((unsigned)f2bf(vs[2 * q + 1]) << 16);
          Cw[(size_t)row * 128 + (col0 >> 1) + wc * 32 + q * 16 + c16] = wv;
        }
      }
    }
  }
}

// ---------------- GAT aggregation: single pass, 8-deep gather (R9 form) ----------
__global__ __launch_bounds__(256) void gat_agg(
    const ushort_t* __restrict__ hb, const float* __restrict__ as_,
    const float* __restrict__ ad_, const int* __restrict__ row_off,
    const int* __restrict__ col_src, const float* __restrict__ bias,
    ushort_t* __restrict__ outb, int n, int relu_out) {
  int node = blockIdx.x * 4 + (threadIdx.x >> 6);
  int lane = threadIdx.x & 63;
  if (node >= n) return;
  int lo = row_off[node], hi = row_off[node + 1];
  int deg = hi - lo;
  float adn = ad_[node];
  float w_self = __expf(leaky(as_[node] + adn));

  const int q = lane >> 4;
  const int l16 = lane & 15;
  const ushort_t* rowbase = hb + (size_t)l16 * 16;

  float acc[16];
  float zacc = (lane == 0) ? w_self : 0.f;
  {
    const uint4* ps = (const uint4*)(rowbase + (size_t)node * 256);
    uint4 v0 = ps[0], v1 = ps[1];
    float ws = (q == 0) ? w_self : 0.f;
    float f[16];
    unpack8(v0, f);
    unpack8(v1, f + 8);
#pragma unroll
    for (int i = 0; i < 16; i++) acc[i] = ws * f[i];
  }

  for (int base = 0; base < deg; base += 64) {
    int cnt = min(64, deg - base);
    int s = 0; float w = 0.f;
    if (lane < cnt) {
      s = col_src[lo + base + lane];
      w = __expf(leaky(as_[s] + adn));
    }
    zacc += w;
    int e = 0;
    for (; e + 8 <= cnt; e += 8) {
      int iA = e + q, iB = e + 4 + q;
      int sA = __shfl(s, iA);
      float wA = __shfl(w, iA);
      int sB = __shfl(s, iB);
      float wB = __shfl(w, iB);
      const uint4* pA = (const uint4*)(rowbase + (size_t)sA * 256);
      const uint4* pB = (const uint4*)(rowbase + (size_t)sB * 256);
      uint4 a0 = pA[0], a1 = pA[1];
      uint4 b0 = pB[0], b1 = pB[1];
      float f[16];
      unpack8(a0, f);
      unpack8(a1, f + 8);
#pragma unroll
      for (int i = 0; i < 16; i++) acc[i] = fmaf(wA, f[i], acc[i]);
      unpack8(b0, f);
      unpack8(b1, f + 8);
#pragma unroll
      for (int i = 0; i < 16; i++) acc[i] = fmaf(wB, f[i], acc[i]);
    }
    for (; e < cnt; e += 4) {
      int myE = e + q;
      int idx = myE < cnt ? myE : cnt - 1;
      int ss = __shfl(s, idx);
      float wv = __shfl(w, idx);
      float wgt = (myE < cnt) ? wv : 0.f;
      const uint4* pp = (const uint4*)(rowbase + (size_t)ss * 256);
      uint4 v0 = pp[0], v1 = pp[1];
      float f[16];
      unpack8(v0, f);
      unpack8(v1, f + 8);
#pragma unroll
      for (int i = 0; i < 16; i++) acc[i] = fmaf(wgt, f[i], acc[i]);
    }
  }

  float z = wave_sum(zacc);
  float inv_z = 1.0f / z;

#pragma unroll
  for (int i = 0; i < 16; i++) {
    acc[i] += __shfl_xor(acc[i], 16);
    acc[i] += __shfl_xor(acc[i], 32);
  }

  if (q == 0) {
    float o[16];
#pragma unroll
    for (int i = 0; i < 16; i += 4) {
      float4 bb = *(const float4*)&bias[l16 * 16 + i];
      o[i]     = fmaf(acc[i],     inv_z, bb.x);
      o[i + 1] = fmaf(acc[i + 1], inv_z, bb.y);
      o[i + 2] = fmaf(acc[i + 2], inv_z, bb.z);
      o[i + 3] = fmaf(acc[i + 3], inv_z, bb.w);
    }
    if (relu_out) {
#pragma unroll
      for (int i = 0; i < 16; i++) o[i] = fmaxf(o[i], 0.f);
    }
    uint4* op = (uint4*)(outb + (size_t)node * 256 + l16 * 16);
    op[0] = pack8(o);
    op[1] = pack8(o + 8);
  }
}

// ---------------- BN stats (bf16 input, stored space) ----------------
__global__ __launch_bounds__(256) void bn_stats(const ushort_t* __restrict__ h, int n,
                                                float* __restrict__ bsum,
                                                float* __restrict__ bsq) {
  int c = threadIdx.x;
  int rows_per_block = (n + gridDim.x - 1) / gridDim.x;
  int r0 = blockIdx.x * rows_per_block;
  int r1 = min(r0 + rows_per_block, n);
  float sum = 0.f, sq = 0.f;
  for (int r = r0; r < r1; r++) {
    float v = bf2f(h[(size_t)r * 256 + c]);
    sum += v;
    sq = fmaf(v, v, sq);
  }
  atomicAdd(&bsum[c], sum);
  atomicAdd(&bsq[c], sq);
}

// ---------------- BN apply + ReLU (bf16 -> bf16, stored space) ----------------
__global__ __launch_bounds__(256) void bn_apply(const ushort_t* __restrict__ h,
                                                const float* __restrict__ bsum,
                                                const float* __restrict__ bsq,
                                                const float* __restrict__ gamma,
                                                const float* __restrict__ beta,
                                                ushort_t* __restrict__ h2b, int n) {
  int total4 = n * 64;
  float inv_n = 1.0f / (float)n;
  for (int f = blockIdx.x * blockDim.x + threadIdx.x; f < total4;
       f += gridDim.x * blockDim.x) {
    int c4 = f & 63;
    uint2 hv = ((const uint2*)h)[f];
    float v0, v1, v2, v3;
    {
      union { unsigned u; float fl; } t;
      t.u = hv.x << 16;         v0 = t.fl;
      t.u = hv.x & 0xFFFF0000u; v1 = t.fl;
      t.u = hv.y << 16;         v2 = t.fl;
      t.u = hv.y & 0xFFFF0000u; v3 = t.fl;
    }
    float4 sm = ((const float4*)bsum)[c4];
    float4 sl = ((const float4*)bsq)[c4];
    float4 g = ((const float4*)gamma)[c4];
    float4 bb = ((const float4*)beta)[c4];
    float m, var;
    m = sm.x * inv_n; var = sl.x * inv_n - m * m;
    v0 = fmaxf(g.x * (v0 - m) * rsqrtf(var + 1e-5f) + bb.x, 0.f);
    m = sm.y * inv_n; var = sl.y * inv_n - m * m;
    v1 = fmaxf(g.y * (v1 - m) * rsqrtf(var + 1e-5f) + bb.y, 0.f);
    m = sm.z * inv_n; var = sl.z * inv_n - m * m;
    v2 = fmaxf(g.z * (v2 - m) * rsqrtf(var + 1e-5f) + bb.z, 0.f);
    m = sm.w * inv_n; var = sl.w * inv_n - m * m;
    v3 = fmaxf(g.w * (v3 - m) * rsqrtf(var + 1e-5f) + bb.w, 0.f);
    uint2 o;
    o.x = (unsigned)f2bf(v0) | ((unsigned)f2bf(v1) << 16);
    o.y = (unsigned)f2bf(v2) | ((unsigned)f2bf(v3) << 16);
    ((uint2*)h2b)[f] = o;
  }
}

// ---------------- mean pool: partial sums ----------------
__device__ inline int lower_bound_dev(const int* a, int n, int v) {
  int lo = 0, hi = n;
  while (lo < hi) {
    int mid = (lo + hi) >> 1;
    if (a[mid] < v) lo = mid + 1; else hi = mid;
  }
  return lo;
}

#define POOL_CHUNKS 16
__global__ __launch_bounds__(256) void pool_partial(const ushort_t* __restrict__ h,
                                                    const int* __restrict__ batch, int n,
                                                    float* __restrict__ psum) {
  int g = blockIdx.x / POOL_CHUNKS;
  int c = blockIdx.x % POOL_CHUNKS;
  int lo = lower_bound_dev(batch, n, g);
  int hi = lower_bound_dev(batch, n, g + 1);
  int len = hi - lo;
  int r0 = lo + (int)(((long long)len * c) / POOL_CHUNKS);
  int r1 = lo + (int)(((long long)len * (c + 1)) / POOL_CHUNKS);
  if (r1 <= r0) return;
  float sum = 0.f;
  for (int r = r0; r < r1; r++) sum += bf2f(h[(size_t)r * 256 + threadIdx.x]);
  atomicAdd(&psum[(size_t)g * 256 + threadIdx.x], sum);
}

// ---------------- final head ----------------
__global__ __launch_bounds__(256) void final_kernel(const float* __restrict__ psum,
                                                    const int* __restrict__ batch, int n,
                                                    const float* __restrict__ ce,
                                                    const float* __restrict__ pWc,
                                                    const float* __restrict__ Wc,
                                                    const float* __restrict__ bc,
                                                    float* __restrict__ out, int B) {
  int g = blockIdx.x;
  int t = threadIdx.x;
  int lo = lower_bound_dev(batch, n, g);
  int hi = lower_bound_dev(batch, n, g + 1);
  float inv_cnt = 1.0f / fmaxf((float)(hi - lo), 1.0f);
  float p = 0.f;
  p = fmaf(psum[(size_t)g * 256 + t] * inv_cnt, pWc[t], p);
  p = fmaf(ce[(size_t)g * 768 + t],        Wc[256 + t], p);
  p = fmaf(ce[(size_t)g * 768 + 256 + t],  Wc[512 + t], p);
  p = fmaf(ce[(size_t)g * 768 + 512 + t],  Wc[768 + t], p);
  __shared__ float red[256];
  red[t] = p;
  __syncthreads();
  for (int s = 128; s; s >>= 1) {
    if (t < s) red[t] += red[t + s];
    __syncthreads();
  }
  if (t == 0) out[g] = red[0] + bc[0];
}

// ---------------- launch ----------------
extern "C" void kernel_launch(void* const* d_in, const int* in_sizes, int n_in,
                              void* d_out, int out_size, void* d_ws, size_t ws_size,
                              hipStream_t stream) {
  const float* ce    = (const float*)d_in[0];
  const float* x     = (const float*)d_in[1];
  const int*   edge  = (const int*)d_in[2];
  const int*   batch = (const int*)d_in[3];
  const float* W1    = (const float*)d_in[4];
  const float* a_s1  = (const float*)d_in[5];
  const float* a_d1  = (const float*)d_in[6];
  const float* b1    = (const float*)d_in[7];
  const float* W2    = (const float*)d_in[8];
  const float* a_s2  = (const float*)d_in[9];
  const float* a_d2  = (const float*)d_in[10];
  const float* b2    = (const float*)d_in[11];
  const float* gamma = (const float*)d_in[12];
  const float* beta  = (const float*)d_in[13];
  const float* Wc    = (const float*)d_in[14];
  const float* bc    = (const float*)d_in[15];

  const int B = in_sizes[0] / DIN;
  const int n = in_sizes[1] / DIN;
  const int E = in_sizes[2] / 2;
  const int* esrc = edge;
  const int* edst = edge + E;

  char* w = (char*)d_ws;
  size_t off = 0;
  auto carve = [&](size_t bytes) -> void* {
    void* p = w + off;
    off = (off + bytes + 255) & ~(size_t)255;
    return p;
  };
  size_t hbytes = (size_t)n * DH * 2;            // 25.6 MB
  char*  R1      = (char*)carve((size_t)n * DIN * 2);
  ushort_t* xb    = (ushort_t*)R1;
  ushort_t* h1b   = (ushort_t*)R1;
  ushort_t* h2b   = (ushort_t*)(R1 + hbytes);
  ushort_t* buf_ob = (ushort_t*)(R1 + 2 * hbytes);
  ushort_t* buf_hb = (ushort_t*)carve(hbytes);   // GEMM output (both layers)
  int*   row_off = (int*)carve((size_t)(n + 1) * 4);
  int*   col_src = (int*)carve((size_t)E * 4);
  ushort_t* Wt1  = (ushort_t*)carve((size_t)DIN * DH * 2);
  ushort_t* Wt2  = (ushort_t*)carve((size_t)DH * DH * 2);
  float* pb1     = (float*)carve(DH * 4);
  float* pb2     = (float*)carve(DH * 4);
  float* pgamma  = (float*)carve(DH * 4);
  float* pbeta   = (float*)carve(DH * 4);
  float* pWc     = (float*)carve(DH * 4);
  float* cenorm  = (float*)carve((size_t)B * 4);
  float* rel     = (float*)carve((size_t)n * 4);
  int*   sc_bsum = (int*)carve(256 * 4);
  int*   sc_boff = (int*)carve(256 * 4);
  char* zero0 = (char*)carve((size_t)n * 4);     // cnt
  int*   cnt     = (int*)zero0;
  int*   fill    = (int*)carve((size_t)n * 4);
  float* as1buf  = (float*)carve((size_t)n * 4);
  float* ad1buf  = (float*)carve((size_t)n * 4);
  float* as2buf  = (float*)carve((size_t)n * 4);
  float* ad2buf  = (float*)carve((size_t)n * 4);
  float* bn_sum  = (float*)carve(DH * 4);
  float* bn_sq   = (float*)carve(DH * 4);
  float* psum    = (float*)carve((size_t)B * DH * 4);
  size_t zero_bytes = (size_t)((char*)(psum + (size_t)B * DH) - zero0);

  hipMemsetAsync(zero0, 0, zero_bytes, stream);

  const int gN4 = (n + 3) / 4;
  const int Mb = (n + 127) / 128;
  const int nb = (n + 255) / 256;   // scan blocks (<=256 for n<=65536)

  prep_kernel<<<66, 256, 0, stream>>>(W1, W2, b1, b2, gamma, beta, Wc, ce,
                                      Wt1, Wt2, pb1, pb2, pgamma, pbeta, pWc,
                                      cenorm, B);
  relxb_hist_kernel<<<gN4, 256, 0, stream>>>(ce, x, batch, cenorm, xb, rel, n,
                                             edst, E, cnt);
  scan1_kernel<<<nb, 256, 0, stream>>>(cnt, row_off, sc_bsum, n);
  scan2_kernel<<<1, 256, 0, stream>>>(sc_bsum, sc_boff, nb, row_off, n);
  scan3_kernel<<<nb, 256, 0, stream>>>(row_off, sc_boff, n);
  fill_kernel<<<1024, 256, 0, stream>>>(esrc, edst, E, row_off, fill, col_src);

  // ---- layer 1 (rel applied as row-scale in epilogue) ----
  gemm_mfma<DIN><<<dim3(2, Mb), 256, 0, stream>>>(xb, Wt1, buf_hb, rel, a_s1,
                                                  a_d1, as1buf, ad1buf, n);
  gat_agg<<<gN4, 256, 0, stream>>>(buf_hb, as1buf, ad1buf, row_off, col_src, pb1,
                                   h1b, n, 0);
  bn_stats<<<512, 256, 0, stream>>>(h1b, n, bn_sum, bn_sq);
  bn_apply<<<2048, 256, 0, stream>>>(h1b, bn_sum, bn_sq, pgamma, pbeta, h2b, n);

  // ---- layer 2 ----
  gemm_mfma<DH><<<dim3(2, Mb), 256, 0, stream>>>(h2b, Wt2, buf_hb, nullptr, a_s2,
                                                 a_d2, as2buf, ad2buf, n);
  gat_agg<<<gN4, 256, 0, stream>>>(buf_hb, as2buf, ad2buf, row_off, col_src, pb2,
                                   buf_ob, n, 1);

  // ---- head ----
  pool_partial<<<B * POOL_CHUNKS, 256, 0, stream>>>(buf_ob, batch, n, psum);
  final_kernel<<<B, 256, 0, stream>>>(psum, batch, n, ce, pWc, Wc, bc,
                                      (float*)d_out, B);
}

// Round 13
// 373.920 us; speedup vs baseline: 1.2174x; 1.1173x over previous
//
#include <hip/hip_runtime.h>
#include <hip/hip_bf16.h>

#define DIN 768
#define DH  256

typedef unsigned short ushort_t;
typedef unsigned char uchar_t;
typedef __attribute__((ext_vector_type(8))) short short8v;   // 8 bf16 (4 VGPRs)
typedef __attribute__((ext_vector_type(4))) float f32x4;
typedef __attribute__((ext_vector_type(2))) float f32x2;

// stored-col s -> original-col (fp8 pack-of-4 layout, per 128-col block):
//   u=(s>>2)&31, nn=s&3 -> orig = (u>>4)*64 + nn*16 + (u&15)
__host__ __device__ inline int orig_col(int s) {
  int u = (s >> 2) & 31;
  return (s & ~127) | (((u >> 4) & 1) << 6) | ((s & 3) << 4) | (u & 15);
}

__device__ inline float wave_sum(float v) {
#pragma unroll
  for (int o = 32; o; o >>= 1) v += __shfl_xor(v, o);
  return v;
}
__device__ inline void wave_sum2(float& a, float& b) {
#pragma unroll
  for (int o = 32; o; o >>= 1) {
    a += __shfl_xor(a, o);
    b += __shfl_xor(b, o);
  }
}
__device__ inline float leaky(float v) { return v > 0.f ? v : 0.2f * v; }

__device__ inline ushort_t f2bf(float f) {
  union { float f; unsigned u; } v; v.f = f;
  unsigned r = v.u + 0x7FFFu + ((v.u >> 16) & 1u);  // RNE
  return (ushort_t)(r >> 16);
}
__device__ inline float bf2f(ushort_t u) {
  union { unsigned u; float f; } t; t.u = ((unsigned)u) << 16; return t.f;
}

// 16 fp8 (uint4) -> 16 f32 via HW packed converts
__device__ inline void unpack16f8(uint4 v, float* f) {
  f32x2 p;
  p = __builtin_amdgcn_cvt_pk_f32_fp8(v.x, false); f[0] = p[0]; f[1] = p[1];
  p = __builtin_amdgcn_cvt_pk_f32_fp8(v.x, true);  f[2] = p[0]; f[3] = p[1];
  p = __builtin_amdgcn_cvt_pk_f32_fp8(v.y, false); f[4] = p[0]; f[5] = p[1];
  p = __builtin_amdgcn_cvt_pk_f32_fp8(v.y, true);  f[6] = p[0]; f[7] = p[1];
  p = __builtin_amdgcn_cvt_pk_f32_fp8(v.z, false); f[8] = p[0]; f[9] = p[1];
  p = __builtin_amdgcn_cvt_pk_f32_fp8(v.z, true);  f[10] = p[0]; f[11] = p[1];
  p = __builtin_amdgcn_cvt_pk_f32_fp8(v.w, false); f[12] = p[0]; f[13] = p[1];
  p = __builtin_amdgcn_cvt_pk_f32_fp8(v.w, true);  f[14] = p[0]; f[15] = p[1];
}
__device__ inline uint4 pack8(const float* f) {
  uint4 o;
  o.x = (unsigned)f2bf(f[0]) | ((unsigned)f2bf(f[1]) << 16);
  o.y = (unsigned)f2bf(f[2]) | ((unsigned)f2bf(f[3]) << 16);
  o.z = (unsigned)f2bf(f[4]) | ((unsigned)f2bf(f[5]) << 16);
  o.w = (unsigned)f2bf(f[6]) | ((unsigned)f2bf(f[7]) << 16);
  return o;
}

// ---------------- K1: cosine gate (rel only) + bf16(x) cast + fused histogram ------
__global__ __launch_bounds__(256) void relxb_hist_kernel(
    const float* __restrict__ ce, const float* __restrict__ x,
    const int* __restrict__ batch, const float* __restrict__ cenorm,
    ushort_t* __restrict__ xb, float* __restrict__ rel, int n,
    const int* __restrict__ edst, int E, int* __restrict__ cnt) {
  int node = blockIdx.x * 4 + (threadIdx.x >> 6);
  int lane = threadIdx.x & 63;
  if (node < n) {
    int g = batch[node];
    const float4* xr = (const float4*)(x + (size_t)node * DIN);
    const float4* cr = (const float4*)(ce + (size_t)g * DIN);
    float dxy = 0.f, dxx = 0.f;
#pragma unroll
    for (int i = 0; i < 3; i++) {
      float4 a = xr[lane + 64 * i];
      float4 b = cr[lane + 64 * i];
      ushort4 o = make_ushort4(f2bf(a.x), f2bf(a.y), f2bf(a.z), f2bf(a.w));
      *(ushort4*)&xb[(size_t)node * DIN + (lane + 64 * i) * 4] = o;
      dxy += a.x*b.x + a.y*b.y + a.z*b.z + a.w*b.w;
      dxx += a.x*a.x + a.y*a.y + a.z*a.z + a.w*a.w;
    }
    wave_sum2(dxy, dxx);
    if (lane == 0) {
      float denom = fmaxf(sqrtf(dxx) * cenorm[g], 1e-8f);
      rel[node] = dxy / denom;
    }
  }
  for (int e = blockIdx.x * blockDim.x + threadIdx.x; e < E;
       e += gridDim.x * blockDim.x)
    atomicAdd(&cnt[edst[e]], 1);
}

// ---------------- prep: Wt tiles + permuted vectors + per-graph ce norms ----------
__global__ __launch_bounds__(256) void prep_kernel(
    const float* __restrict__ W1, const float* __restrict__ W2,
    const float* __restrict__ b1, const float* __restrict__ b2,
    const float* __restrict__ gamma, const float* __restrict__ beta,
    const float* __restrict__ Wc, const float* __restrict__ ce,
    ushort_t* __restrict__ Wt1, ushort_t* __restrict__ Wt2,
    float* __restrict__ pb1, float* __restrict__ pb2,
    float* __restrict__ pgamma, float* __restrict__ pbeta,
    float* __restrict__ pWc, float* __restrict__ cenorm, int B) {
  __shared__ float tile[64][65];
  int b = blockIdx.x;
  int t = threadIdx.x;
  int r4 = t >> 6;
  int c64 = t & 63;
  if (b < 48) {
    int k0 = (b % 12) * 64, c0 = (b / 12) * 64;
#pragma unroll
    for (int rr = 0; rr < 16; rr++) {
      int r = rr * 4 + r4;
      tile[r][c64] = W1[(size_t)(k0 + r) * 256 + c0 + c64];
    }
    __syncthreads();
#pragma unroll
    for (int rr = 0; rr < 16; rr++) {
      int cc = rr * 4 + r4;
      Wt1[(size_t)(c0 + cc) * DIN + k0 + c64] = f2bf(tile[c64][cc]);
    }
  } else if (b < 64) {
    int bb = b - 48;
    int k0 = (bb & 3) * 64, c0 = (bb >> 2) * 64;
#pragma unroll
    for (int rr = 0; rr < 16; rr++) {
      int r = rr * 4 + r4;
      tile[r][c64] = W2[(size_t)orig_col(k0 + r) * 256 + c0 + c64];
    }
    __syncthreads();
#pragma unroll
    for (int rr = 0; rr < 16; rr++) {
      int cc = rr * 4 + r4;
      Wt2[(size_t)(c0 + cc) * DH + k0 + c64] = f2bf(tile[c64][cc]);
    }
  } else if (b == 64) {
    int o = orig_col(t);
    pb1[t] = b1[o];
    pb2[t] = b2[o];
    pgamma[t] = gamma[o];
    pbeta[t] = beta[o];
    pWc[t] = Wc[o];
  } else {
    int lane = t & 63;
    for (int g = r4; g < B; g += 4) {
      const float4* cr = (const float4*)(ce + (size_t)g * DIN);
      float s = 0.f;
#pragma unroll
      for (int i = 0; i < 3; i++) {
        float4 v = cr[lane + 64 * i];
        s += v.x*v.x + v.y*v.y + v.z*v.z + v.w*v.w;
      }
      s = wave_sum(s);
      if (lane == 0) cenorm[g] = sqrtf(s);
    }
  }
}

// ---------------- CSR: parallel 3-phase scan + fill ----------------
__global__ __launch_bounds__(256) void scan1_kernel(const int* __restrict__ cnt,
                                                    int* __restrict__ row_off,
                                                    int* __restrict__ bsum, int n) {
  __shared__ int s[256];
  int t = threadIdx.x;
  int i = blockIdx.x * 256 + t;
  int v = (i < n) ? cnt[i] : 0;
  s[t] = v;
  __syncthreads();
  for (int off = 1; off < 256; off <<= 1) {
    int tmp = (t >= off) ? s[t - off] : 0;
    __syncthreads();
    s[t] += tmp;
    __syncthreads();
  }
  if (i < n) row_off[i] = s[t] - v;
  if (t == 255) bsum[blockIdx.x] = s[255];
}

__global__ __launch_bounds__(256) void scan2_kernel(const int* __restrict__ bsum,
                                                    int* __restrict__ boff, int nb,
                                                    int* __restrict__ row_off, int n) {
  __shared__ int s[256];
  int t = threadIdx.x;
  int v = (t < nb) ? bsum[t] : 0;
  s[t] = v;
  __syncthreads();
  for (int off = 1; off < 256; off <<= 1) {
    int tmp = (t >= off) ? s[t - off] : 0;
    __syncthreads();
    s[t] += tmp;
    __syncthreads();
  }
  if (t < nb) boff[t] = s[t] - v;
  if (t == nb - 1) row_off[n] = s[t];
}

__global__ __launch_bounds__(256) void scan3_kernel(int* __restrict__ row_off,
                                                    const int* __restrict__ boff, int n) {
  int i = blockIdx.x * 256 + threadIdx.x;
  if (i < n) row_off[i] += boff[blockIdx.x];
}

__global__ void fill_kernel(const int* __restrict__ src, const int* __restrict__ dst, int E,
                            const int* __restrict__ row_off, int* __restrict__ fill,
                            int* __restrict__ col_src) {
  for (int e = blockIdx.x * blockDim.x + threadIdx.x; e < E; e += gridDim.x * blockDim.x) {
    int d = dst[e];
    int slot = row_off[d] + atomicAdd(&fill[d], 1);
    col_src[slot] = src[e];
  }
}

// ---------------- bf16 MFMA GEMM + row-scale + alpha dots; fp8 C-output -----------
template <int K>
__global__ __launch_bounds__(256) void gemm_mfma(
    const ushort_t* __restrict__ A, const ushort_t* __restrict__ Bt,
    uchar_t* __restrict__ C, const float* __restrict__ scale,
    const float* __restrict__ a_s, const float* __restrict__ a_d,
    float* __restrict__ alpha_s, float* __restrict__ alpha_d, int Mreal) {
  __shared__ ushort_t lds[16384];
  const int tid = threadIdx.x;
  const int lane = tid & 63;
  const int wave = tid >> 6;

  int p = blockIdx.y * 2 + blockIdx.x;
  int total = 2 * gridDim.y;
  int cch = p >> 4;
  int v;
  if ((cch << 4) + 16 <= total) {
    int r = p & 15;
    v = (cch << 4) | ((r & 7) << 1) | (r >> 3);
  } else {
    v = p;
  }
  const int col0 = (v & 1) * 128;
  const int row0 = (v >> 1) * 128;

  const int wr = wave >> 1, wc = wave & 1;
  const int c16 = lane & 15, g4 = lane >> 4;
  const int st_roff = lane >> 3;
  const int st_gsrc = (lane & 7) ^ st_roff;

  f32x4 acc[4][4];
#pragma unroll
  for (int m = 0; m < 4; m++)
#pragma unroll
    for (int nn = 0; nn < 4; nn++)
#pragma unroll
      for (int j = 0; j < 4; j++) acc[m][nn][j] = 0.f;

  for (int k0 = 0; k0 < K; k0 += 64) {
#pragma unroll
    for (int ci = 0; ci < 8; ci++) {
      int inst = wave * 8 + ci;
      int isB = inst >> 4;
      int idx = inst & 15;
      int lrow = idx * 8 + st_roff;
      const ushort_t* gsrc;
      if (isB == 0) {
        int rg = row0 + lrow;
        rg = rg < Mreal ? rg : Mreal - 1;
        gsrc = A + (size_t)rg * K + k0 + st_gsrc * 8;
      } else {
        gsrc = Bt + (size_t)(col0 + lrow) * K + k0 + st_gsrc * 8;
      }
      __builtin_amdgcn_global_load_lds(
          (const __attribute__((address_space(1))) void*)gsrc,
          (__attribute__((address_space(3))) void*)&lds[isB * 8192 + idx * 512],
          16, 0, 0);
    }
    __syncthreads();
#pragma unroll
    for (int ks = 0; ks < 2; ks++) {
      int g = ks * 4 + g4;
      short8v a[4], b[4];
#pragma unroll
      for (int m = 0; m < 4; m++) {
        int ra = wr * 64 + m * 16 + c16;
        a[m] = *(const short8v*)&lds[ra * 64 + (g ^ (ra & 7)) * 8];
      }
#pragma unroll
      for (int nn = 0; nn < 4; nn++) {
        int rb = wc * 64 + nn * 16 + c16;
        b[nn] = *(const short8v*)&lds[8192 + rb * 64 + (g ^ (rb & 7)) * 8];
      }
#pragma unroll
      for (int m = 0; m < 4; m++)
#pragma unroll
        for (int nn = 0; nn < 4; nn++)
          acc[m][nn] = __builtin_amdgcn_mfma_f32_16x16x32_bf16(a[m], b[nn],
                                                               acc[m][nn], 0, 0, 0);
    }
    __syncthreads();
  }

  float asv[4], adv[4];
#pragma unroll
  for (int nn = 0; nn < 4; nn++) {
    int col = col0 + wc * 64 + nn * 16 + c16;
    asv[nn] = a_s[col];
    adv[nn] = a_d[col];
  }

  uint* Cw = (uint*)C;   // fp8 rows: 64 uints (256 B) per row
#pragma unroll
  for (int m = 0; m < 4; m++) {
    int row_base = row0 + wr * 64 + m * 16 + g4 * 4;
#pragma unroll
    for (int j = 0; j < 4; j++) {
      int row = row_base + j;
      int rc = row < Mreal ? row : Mreal - 1;
      float s = scale ? scale[rc] : 1.0f;
      float vs[4];
      float ps = 0.f, pd = 0.f;
#pragma unroll
      for (int nn = 0; nn < 4; nn++) {
        float v2 = acc[m][nn][j] * s;
        vs[nn] = v2;
        ps = fmaf(v2, asv[nn], ps);
        pd = fmaf(v2, adv[nn], pd);
      }
#pragma unroll
      for (int o = 1; o < 16; o <<= 1) {
        ps += __shfl_xor(ps, o);
        pd += __shfl_xor(pd, o);
      }
      if (c16 == 0 && row < Mreal) {
        atomicAdd(&alpha_s[row], ps);
        atomicAdd(&alpha_d[row], pd);
      }
      if (row < Mreal) {
        unsigned w8 = __builtin_amdgcn_cvt_pk_fp8_f32(vs[0], vs[1], 0u, false);
        w8 = __builtin_amdgcn_cvt_pk_fp8_f32(vs[2], vs[3], w8, true);
        Cw[(size_t)row * 64 + (col0 >> 2) + wc * 16 + c16] = w8;
      }
    }
  }
}

// ---------------- GAT aggregation: single pass, fp8 gather (256B rows) -----------
__global__ __launch_bounds__(256) void gat_agg(
    const uchar_t* __restrict__ h8, const float* __restrict__ as_,
    const float* __restrict__ ad_, const int* __restrict__ row_off,
    const int* __restrict__ col_src, const float* __restrict__ bias,
    ushort_t* __restrict__ outb, int n, int relu_out) {
  int node = blockIdx.x * 4 + (threadIdx.x >> 6);
  int lane = threadIdx.x & 63;
  if (node >= n) return;
  int lo = row_off[node], hi = row_off[node + 1];
  int deg = hi - lo;
  float adn = ad_[node];
  float w_self = __expf(leaky(as_[node] + adn));

  const int q = lane >> 4;
  const int l16 = lane & 15;
  const uchar_t* rowbase = h8 + (size_t)l16 * 16;   // lane owns 16 stored cols

  float acc[16];
  float zacc = (lane == 0) ? w_self : 0.f;
  {
    uint4 v = *(const uint4*)(rowbase + (size_t)node * 256);
    float ws = (q == 0) ? w_self : 0.f;
    float f[16];
    unpack16f8(v, f);
#pragma unroll
    for (int i = 0; i < 16; i++) acc[i] = ws * f[i];
  }

  for (int base = 0; base < deg; base += 64) {
    int cnt = min(64, deg - base);
    int s = 0; float w = 0.f;
    if (lane < cnt) {
      s = col_src[lo + base + lane];
      w = __expf(leaky(as_[s] + adn));
    }
    zacc += w;
    int e = 0;
    for (; e + 8 <= cnt; e += 8) {
      int iA = e + q, iB = e + 4 + q;
      int sA = __shfl(s, iA);
      float wA = __shfl(w, iA);
      int sB = __shfl(s, iB);
      float wB = __shfl(w, iB);
      uint4 a0 = *(const uint4*)(rowbase + (size_t)sA * 256);
      uint4 b0 = *(const uint4*)(rowbase + (size_t)sB * 256);
      float f[16];
      unpack16f8(a0, f);
#pragma unroll
      for (int i = 0; i < 16; i++) acc[i] = fmaf(wA, f[i], acc[i]);
      unpack16f8(b0, f);
#pragma unroll
      for (int i = 0; i < 16; i++) acc[i] = fmaf(wB, f[i], acc[i]);
    }
    for (; e < cnt; e += 4) {
      int myE = e + q;
      int idx = myE < cnt ? myE : cnt - 1;
      int ss = __shfl(s, idx);
      float wv = __shfl(w, idx);
      float wgt = (myE < cnt) ? wv : 0.f;
      uint4 v = *(const uint4*)(rowbase + (size_t)ss * 256);
      float f[16];
      unpack16f8(v, f);
#pragma unroll
      for (int i = 0; i < 16; i++) acc[i] = fmaf(wgt, f[i], acc[i]);
    }
  }

  float z = wave_sum(zacc);
  float inv_z = 1.0f / z;

#pragma unroll
  for (int i = 0; i < 16; i++) {
    acc[i] += __shfl_xor(acc[i], 16);
    acc[i] += __shfl_xor(acc[i], 32);
  }

  if (q == 0) {
    float o[16];
#pragma unroll
    for (int i = 0; i < 16; i += 4) {
      float4 bb = *(const float4*)&bias[l16 * 16 + i];
      o[i]     = fmaf(acc[i],     inv_z, bb.x);
      o[i + 1] = fmaf(acc[i + 1], inv_z, bb.y);
      o[i + 2] = fmaf(acc[i + 2], inv_z, bb.z);
      o[i + 3] = fmaf(acc[i + 3], inv_z, bb.w);
    }
    if (relu_out) {
#pragma unroll
      for (int i = 0; i < 16; i++) o[i] = fmaxf(o[i], 0.f);
    }
    uint4* op = (uint4*)(outb + (size_t)node * 256 + l16 * 16);
    op[0] = pack8(o);
    op[1] = pack8(o + 8);
  }
}

// ---------------- BN stats (bf16 input, stored space) ----------------
__global__ __launch_bounds__(256) void bn_stats(const ushort_t* __restrict__ h, int n,
                                                float* __restrict__ bsum,
                                                float* __restrict__ bsq) {
  int c = threadIdx.x;
  int rows_per_block = (n + gridDim.x - 1) / gridDim.x;
  int r0 = blockIdx.x * rows_per_block;
  int r1 = min(r0 + rows_per_block, n);
  float sum = 0.f, sq = 0.f;
  for (int r = r0; r < r1; r++) {
    float v = bf2f(h[(size_t)r * 256 + c]);
    sum += v;
    sq = fmaf(v, v, sq);
  }
  atomicAdd(&bsum[c], sum);
  atomicAdd(&bsq[c], sq);
}

// ---------------- BN apply + ReLU (bf16 -> bf16, stored space) ----------------
__global__ __launch_bounds__(256) void bn_apply(const ushort_t* __restrict__ h,
                                                const float* __restrict__ bsum,
                                                const float* __restrict__ bsq,
                                                const float* __restrict__ gamma,
                                                const float* __restrict__ beta,
                                                ushort_t* __restrict__ h2b, int n) {
  int total4 = n * 64;
  float inv_n = 1.0f / (float)n;
  for (int f = blockIdx.x * blockDim.x + threadIdx.x; f < total4;
       f += gridDim.x * blockDim.x) {
    int c4 = f & 63;
    uint2 hv = ((const uint2*)h)[f];
    float v0, v1, v2, v3;
    {
      union { unsigned u; float fl; } t;
      t.u = hv.x << 16;         v0 = t.fl;
      t.u = hv.x & 0xFFFF0000u; v1 = t.fl;
      t.u = hv.y << 16;         v2 = t.fl;
      t.u = hv.y & 0xFFFF0000u; v3 = t.fl;
    }
    float4 sm = ((const float4*)bsum)[c4];
    float4 sl = ((const float4*)bsq)[c4];
    float4 g = ((const float4*)gamma)[c4];
    float4 bb = ((const float4*)beta)[c4];
    float m, var;
    m = sm.x * inv_n; var = sl.x * inv_n - m * m;
    v0 = fmaxf(g.x * (v0 - m) * rsqrtf(var + 1e-5f) + bb.x, 0.f);
    m = sm.y * inv_n; var = sl.y * inv_n - m * m;
    v1 = fmaxf(g.y * (v1 - m) * rsqrtf(var + 1e-5f) + bb.y, 0.f);
    m = sm.z * inv_n; var = sl.z * inv_n - m * m;
    v2 = fmaxf(g.z * (v2 - m) * rsqrtf(var + 1e-5f) + bb.z, 0.f);
    m = sm.w * inv_n; var = sl.w * inv_n - m * m;
    v3 = fmaxf(g.w * (v3 - m) * rsqrtf(var + 1e-5f) + bb.w, 0.f);
    uint2 o;
    o.x = (unsigned)f2bf(v0) | ((unsigned)f2bf(v1) << 16);
    o.y = (unsigned)f2bf(v2) | ((unsigned)f2bf(v3) << 16);
    ((uint2*)h2b)[f] = o;
  }
}

// ---------------- mean pool: partial sums ----------------
__device__ inline int lower_bound_dev(const int* a, int n, int v) {
  int lo = 0, hi = n;
  while (lo < hi) {
    int mid = (lo + hi) >> 1;
    if (a[mid] < v) lo = mid + 1; else hi = mid;
  }
  return lo;
}

#define POOL_CHUNKS 16
__global__ __launch_bounds__(256) void pool_partial(const ushort_t* __restrict__ h,
                                                    const int* __restrict__ batch, int n,
                                                    float* __restrict__ psum) {
  int g = blockIdx.x / POOL_CHUNKS;
  int c = blockIdx.x % POOL_CHUNKS;
  int lo = lower_bound_dev(batch, n, g);
  int hi = lower_bound_dev(batch, n, g + 1);
  int len = hi - lo;
  int r0 = lo + (int)(((long long)len * c) / POOL_CHUNKS);
  int r1 = lo + (int)(((long long)len * (c + 1)) / POOL_CHUNKS);
  if (r1 <= r0) return;
  float sum = 0.f;
  for (int r = r0; r < r1; r++) sum += bf2f(h[(size_t)r * 256 + threadIdx.x]);
  atomicAdd(&psum[(size_t)g * 256 + threadIdx.x], sum);
}

// ---------------- final head ----------------
__global__ __launch_bounds__(256) void final_kernel(const float* __restrict__ psum,
                                                    const int* __restrict__ batch, int n,
                                                    const float* __restrict__ ce,
                                                    const float* __restrict__ pWc,
                                                    const float* __restrict__ Wc,
                                                    const float* __restrict__ bc,
                                                    float* __restrict__ out, int B) {
  int g = blockIdx.x;
  int t = threadIdx.x;
  int lo = lower_bound_dev(batch, n, g);
  int hi = lower_bound_dev(batch, n, g + 1);
  float inv_cnt = 1.0f / fmaxf((float)(hi - lo), 1.0f);
  float p = 0.f;
  p = fmaf(psum[(size_t)g * 256 + t] * inv_cnt, pWc[t], p);
  p = fmaf(ce[(size_t)g * 768 + t],        Wc[256 + t], p);
  p = fmaf(ce[(size_t)g * 768 + 256 + t],  Wc[512 + t], p);
  p = fmaf(ce[(size_t)g * 768 + 512 + t],  Wc[768 + t], p);
  __shared__ float red[256];
  red[t] = p;
  __syncthreads();
  for (int s = 128; s; s >>= 1) {
    if (t < s) red[t] += red[t + s];
    __syncthreads();
  }
  if (t == 0) out[g] = red[0] + bc[0];
}

// ---------------- launch ----------------
extern "C" void kernel_launch(void* const* d_in, const int* in_sizes, int n_in,
                              void* d_out, int out_size, void* d_ws, size_t ws_size,
                              hipStream_t stream) {
  const float* ce    = (const float*)d_in[0];
  const float* x     = (const float*)d_in[1];
  const int*   edge  = (const int*)d_in[2];
  const int*   batch = (const int*)d_in[3];
  const float* W1    = (const float*)d_in[4];
  const float* a_s1  = (const float*)d_in[5];
  const float* a_d1  = (const float*)d_in[6];
  const float* b1    = (const float*)d_in[7];
  const float* W2    = (const float*)d_in[8];
  const float* a_s2  = (const float*)d_in[9];
  const float* a_d2  = (const float*)d_in[10];
  const float* b2    = (const float*)d_in[11];
  const float* gamma = (const float*)d_in[12];
  const float* beta  = (const float*)d_in[13];
  const float* Wc    = (const float*)d_in[14];
  const float* bc    = (const float*)d_in[15];

  const int B = in_sizes[0] / DIN;
  const int n = in_sizes[1] / DIN;
  const int E = in_sizes[2] / 2;
  const int* esrc = edge;
  const int* edst = edge + E;

  char* w = (char*)d_ws;
  size_t off = 0;
  auto carve = [&](size_t bytes) -> void* {
    void* p = w + off;
    off = (off + bytes + 255) & ~(size_t)255;
    return p;
  };
  size_t hbytes  = (size_t)n * DH * 2;           // bf16 h (25.6 MB)
  size_t h8bytes = (size_t)n * DH;               // fp8 h (12.8 MB)
  char*  R1      = (char*)carve((size_t)n * DIN * 2);
  ushort_t* xb    = (ushort_t*)R1;
  ushort_t* h1b   = (ushort_t*)R1;
  ushort_t* h2b   = (ushort_t*)(R1 + hbytes);
  ushort_t* buf_ob = (ushort_t*)(R1 + 2 * hbytes);
  uchar_t* buf_h8 = (uchar_t*)carve(h8bytes);    // fp8 GEMM output (both layers)
  int*   row_off = (int*)carve((size_t)(n + 1) * 4);
  int*   col_src = (int*)carve((size_t)E * 4);
  ushort_t* Wt1  = (ushort_t*)carve((size_t)DIN * DH * 2);
  ushort_t* Wt2  = (ushort_t*)carve((size_t)DH * DH * 2);
  float* pb1     = (float*)carve(DH * 4);
  float* pb2     = (float*)carve(DH * 4);
  float* pgamma  = (float*)carve(DH * 4);
  float* pbeta   = (float*)carve(DH * 4);
  float* pWc     = (float*)carve(DH * 4);
  float* cenorm  = (float*)carve((size_t)B * 4);
  float* rel     = (float*)carve((size_t)n * 4);
  int*   sc_bsum = (int*)carve(256 * 4);
  int*   sc_boff = (int*)carve(256 * 4);
  char* zero0 = (char*)carve((size_t)n * 4);     // cnt
  int*   cnt     = (int*)zero0;
  int*   fill    = (int*)carve((size_t)n * 4);
  float* as1buf  = (float*)carve((size_t)n * 4);
  float* ad1buf  = (float*)carve((size_t)n * 4);
  float* as2buf  = (float*)carve((size_t)n * 4);
  float* ad2buf  = (float*)carve((size_t)n * 4);
  float* bn_sum  = (float*)carve(DH * 4);
  float* bn_sq   = (float*)carve(DH * 4);
  float* psum    = (float*)carve((size_t)B * DH * 4);
  size_t zero_bytes = (size_t)((char*)(psum + (size_t)B * DH) - zero0);

  hipMemsetAsync(zero0, 0, zero_bytes, stream);

  const int gN4 = (n + 3) / 4;
  const int Mb = (n + 127) / 128;
  const int nb = (n + 255) / 256;

  prep_kernel<<<66, 256, 0, stream>>>(W1, W2, b1, b2, gamma, beta, Wc, ce,
                                      Wt1, Wt2, pb1, pb2, pgamma, pbeta, pWc,
                                      cenorm, B);
  relxb_hist_kernel<<<gN4, 256, 0, stream>>>(ce, x, batch, cenorm, xb, rel, n,
                                             edst, E, cnt);
  scan1_kernel<<<nb, 256, 0, stream>>>(cnt, row_off, sc_bsum, n);
  scan2_kernel<<<1, 256, 0, stream>>>(sc_bsum, sc_boff, nb, row_off, n);
  scan3_kernel<<<nb, 256, 0, stream>>>(row_off, sc_boff, n);
  fill_kernel<<<1024, 256, 0, stream>>>(esrc, edst, E, row_off, fill, col_src);

  // ---- layer 1 (rel as epilogue row-scale; fp8 h out) ----
  gemm_mfma<DIN><<<dim3(2, Mb), 256, 0, stream>>>(xb, Wt1, buf_h8, rel, a_s1,
                                                  a_d1, as1buf, ad1buf, n);
  gat_agg<<<gN4, 256, 0, stream>>>(buf_h8, as1buf, ad1buf, row_off, col_src, pb1,
                                   h1b, n, 0);
  bn_stats<<<512, 256, 0, stream>>>(h1b, n, bn_sum, bn_sq);
  bn_apply<<<2048, 256, 0, stream>>>(h1b, bn_sum, bn_sq, pgamma, pbeta, h2b, n);

  // ---- layer 2 ----
  gemm_mfma<DH><<<dim3(2, Mb), 256, 0, stream>>>(h2b, Wt2, buf_h8, nullptr, a_s2,
                                                 a_d2, as2buf, ad2buf, n);
  gat_agg<<<gN4, 256, 0, stream>>>(buf_h8, as2buf, ad2buf, row_off, col_src, pb2,
                                   buf_ob, n, 1);

  // ---- head ----
  pool_partial<<<B * POOL_CHUNKS, 256, 0, stream>>>(buf_ob, batch, n, psum);
  final_kernel<<<B, 256, 0, stream>>>(psum, batch, n, ce, pWc, Wc, bc,
                                      (float*)d_out, B);
}